// Round 3
// baseline (1229.004 us; speedup 1.0000x reference)
//
#include <hip/hip_runtime.h>
#include <hip/hip_bf16.h>
#include <math.h>

#define NB   16
#define CIN  128
#define COUT 128
#define HH   56
#define WW   56
#define LL   (HH*WW)          // 3136
#define CHUNK 32
#define NCHUNK (CIN/CHUNK)

#define XS_SZ (CHUNK*3*58)    // 5568 floats: x window [cc][3 rows][58 cols]
#define WT_PITCH 129
#define WT_SZ (CHUNK*WT_PITCH)// 4128 floats
#define EPI_SZ (COUT*WW)      // 7168

// workspace layout (bytes):
//   [0,4)            uint32 worklist counter (memsetAsync'd to 0)
//   [256, 256+9216)  float  cos/sin tables  [2][9][128]
//   [12288, +18432)  double cos/sin tables  [2][9][128]
//   [30720, ...)     uint32 worklist entries
#define CSF_OFF   256
#define CSD_OFF   12288
#define WL_OFF    30720

#define TAU_A 1e-3f
#define TAU_B 1e-4f

__global__ void prep_tables(const float* __restrict__ bk, float* __restrict__ csf,
                            double* __restrict__ csd) {
    int i = blockIdx.x * blockDim.x + threadIdx.x;
    if (i < 9*COUT) {
        double v = (double)bk[i];
        double c = cos(v), s = sin(v);
        csf[i]          = (float)c;
        csf[9*COUT + i] = (float)s;
        csd[i]          = c;
        csd[9*COUT + i] = s;
    }
}

__global__ __launch_bounds__(512, 2)
void conv_phase_kernel(const float* __restrict__ x, const float* __restrict__ w,
                       const float* __restrict__ cs, const float* __restrict__ bias,
                       float* __restrict__ out,
                       unsigned* __restrict__ cnt, unsigned* __restrict__ wl,
                       unsigned cap) {
    __shared__ float smem[2*EPI_SZ];   // 57.3 KB
    float* xs = smem;                  // [XS_SZ]
    float* wt = smem + XS_SZ;          // [WT_SZ]

    const int tid    = threadIdx.x;
    const int b      = blockIdx.x / HH;
    const int y      = blockIdx.x % HH;
    const int oc_grp = tid & 63;
    const int px_grp = tid >> 6;

    float acc_a[7][2], acc_b[7][2];
    #pragma unroll
    for (int i = 0; i < 7; i++) { acc_a[i][0]=0.f; acc_a[i][1]=0.f; acc_b[i][0]=0.f; acc_b[i][1]=0.f; }

    const float* xb = x + (size_t)b * CIN * LL;

    for (int ch = 0; ch < NCHUNK; ch++) {
        const int c0 = ch * CHUNK;
        __syncthreads();
        for (int s = tid; s < XS_SZ; s += 512) {
            int cc  = s / 174;
            int rem = s - cc*174;
            int r   = rem / 58;
            int col = rem - r*58;
            int row  = y + r - 1;
            int gcol = col - 1;
            float v = 0.0f;
            if ((unsigned)row < HH && (unsigned)gcol < WW)
                v = xb[(size_t)(c0+cc)*LL + row*WW + gcol];
            xs[s] = v;
        }
        for (int k = 0; k < 9; k++) {
            const int dy = k / 3, dx = k - dy*3;
            __syncthreads();
            for (int s = tid; s < CHUNK*COUT; s += 512) {
                int oc = s >> 5;
                int cc = s & 31;
                wt[cc*WT_PITCH + oc] = w[k*(COUT*CIN) + oc*CIN + c0 + cc];
            }
            __syncthreads();

            float dot[7][2];
            #pragma unroll
            for (int i = 0; i < 7; i++) { dot[i][0]=0.f; dot[i][1]=0.f; }

            #pragma unroll 4
            for (int cc = 0; cc < CHUNK; cc++) {
                float xv[7];
                #pragma unroll
                for (int i = 0; i < 7; i++)
                    xv[i] = xs[cc*174 + dy*58 + px_grp + 8*i + dx];
                float w0 = wt[cc*WT_PITCH + oc_grp];
                float w1 = wt[cc*WT_PITCH + oc_grp + 64];
                #pragma unroll
                for (int i = 0; i < 7; i++) {
                    dot[i][0] = fmaf(xv[i], w0, dot[i][0]);
                    dot[i][1] = fmaf(xv[i], w1, dot[i][1]);
                }
            }
            float ck0 = cs[k*COUT + oc_grp];
            float ck1 = cs[k*COUT + oc_grp + 64];
            float sk0 = cs[9*COUT + k*COUT + oc_grp];
            float sk1 = cs[9*COUT + k*COUT + oc_grp + 64];
            #pragma unroll
            for (int i = 0; i < 7; i++) {
                acc_a[i][0] = fmaf(ck0, dot[i][0], acc_a[i][0]);
                acc_a[i][1] = fmaf(ck1, dot[i][1], acc_a[i][1]);
                acc_b[i][0] = fmaf(sk0, dot[i][0], acc_b[i][0]);
                acc_b[i][1] = fmaf(sk1, dot[i][1], acc_b[i][1]);
            }
        }
    }

    // ---- epilogue ----
    __syncthreads();
    float* conv_s  = smem;
    float* theta_s = smem + EPI_SZ;
    const float eps = 1e-05f;
    const float PIf = 3.14159265358979323846f;

    #pragma unroll
    for (int j = 0; j < 2; j++) {
        int oc = oc_grp + 64*j;
        float bsv = bias[oc];
        #pragma unroll
        for (int i = 0; i < 7; i++) {
            int px = px_grp + 8*i;
            float av = acc_a[i][j], bv = acc_b[i][j];

            // flag near-discontinuity elements for fp64 fixup
            if (fabsf(av) < TAU_A || fabsf(bv) < TAU_B) {
                unsigned slot = atomicAdd(cnt, 1u);
                if (slot < cap)
                    wl[slot] = ((unsigned)(b*LL + y*WW + px) << 7) | (unsigned)oc;
            }

            bool ag = av > 0.f, bg = bv > 0.f;
            bool eq = (ag == bg);
            float ratio = eq ? (bv / (av + eps)) : (av / (bv + eps));
            float at = atanf(ratio);
            if (!eq) at = -at;
            float peak = eq ? (ag ? PIf*0.5f : -PIf*0.5f) : (bg ? 0.0f : -PIf);
            float th = peak - at;
            float o  = sinf(th)*av + cosf(th)*bv + bsv;
            conv_s[oc*WW + px]  = o;
            theta_s[oc*WW + px] = th * (1.0f/PIf);
        }
    }
    __syncthreads();
    size_t obase = ((size_t)b*(2*COUT))*LL + (size_t)y*WW;
    for (int s = tid; s < EPI_SZ; s += 512) {
        int oc = s / WW;
        int px = s - oc*WW;
        out[obase + (size_t)oc*LL + px]          = conv_s[s];
        out[obase + (size_t)(oc + COUT)*LL + px] = theta_s[s];
    }
}

// one wave per flagged element: exact fp64 recompute of a, bb, theta, o
__global__ __launch_bounds__(256)
void fixup_kernel(const float* __restrict__ x, const float* __restrict__ w,
                  const double* __restrict__ csd, const float* __restrict__ bias,
                  const unsigned* __restrict__ cnt, const unsigned* __restrict__ wl,
                  unsigned cap, float* __restrict__ out) {
    const int lane   = threadIdx.x & 63;
    const int waveid = (blockIdx.x * 256 + threadIdx.x) >> 6;
    const int nwaves = gridDim.x * 4;
    unsigned n = *cnt; if (n > cap) n = cap;
    const double PI = 3.14159265358979323846;

    for (unsigned u = waveid; u < n; u += nwaves) {
        unsigned idx = wl[u];
        int oc = idx & 127;
        unsigned rest = idx >> 7;
        int bb_ = rest / LL;
        int l   = rest - bb_*LL;
        int yy  = l / WW;
        int xx  = l - yy*WW;
        const float* xb = x + (size_t)bb_ * CIN * LL;

        double pa = 0.0, pb = 0.0;
        #pragma unroll
        for (int k = 0; k < 9; k++) {
            int dy = k/3, dx = k - dy*3;
            int py = yy + dy - 1, px = xx + dx - 1;
            double pk = 0.0;
            if ((unsigned)py < HH && (unsigned)px < WW) {
                int base = py*WW + px;
                const float* wr = w + k*(COUT*CIN) + oc*CIN;
                int c = lane;
                pk  = (double)xb[(size_t)c*LL + base] * (double)wr[c];
                c = lane + 64;
                pk += (double)xb[(size_t)c*LL + base] * (double)wr[c];
            }
            pa += csd[k*COUT + oc] * pk;
            pb += csd[9*COUT + k*COUT + oc] * pk;
        }
        #pragma unroll
        for (int off = 32; off > 0; off >>= 1) {
            pa += __shfl_xor(pa, off, 64);
            pb += __shfl_xor(pb, off, 64);
        }
        if (lane == 0) {
            bool ag = pa > 0.0, bg = pb > 0.0;
            bool eq = (ag == bg);
            double th;
            if (eq) th = (ag ? PI*0.5 : -PI*0.5) - atan(pb / (pa + 1e-5));
            else    th = (bg ? 0.0 : -PI) + atan(pa / (pb + 1e-5));
            double o = sin(th)*pa + cos(th)*pb + (double)bias[oc];
            size_t conv_at  = ((size_t)bb_*(2*COUT) + oc) * LL + l;
            size_t theta_at = ((size_t)bb_*(2*COUT) + COUT + oc) * LL + l;
            out[conv_at]  = (float)o;
            out[theta_at] = (float)(th / PI);
        }
    }
}

extern "C" void kernel_launch(void* const* d_in, const int* in_sizes, int n_in,
                              void* d_out, int out_size, void* d_ws, size_t ws_size,
                              hipStream_t stream) {
    const float* x    = (const float*)d_in[0];
    const float* w    = (const float*)d_in[1];
    const float* bk   = (const float*)d_in[2];
    const float* bias = (const float*)d_in[3];
    float* out = (float*)d_out;

    char* ws = (char*)d_ws;
    unsigned* cnt = (unsigned*)ws;
    float*    csf = (float*)(ws + CSF_OFF);
    double*   csd = (double*)(ws + CSD_OFF);
    unsigned* wl  = (unsigned*)(ws + WL_OFF);
    unsigned  cap = (ws_size > WL_OFF + 4096) ? (unsigned)((ws_size - WL_OFF) / 4) : 0u;

    hipMemsetAsync(cnt, 0, 4, stream);
    hipLaunchKernelGGL(prep_tables, dim3(5), dim3(256), 0, stream, bk, csf, csd);
    hipLaunchKernelGGL(conv_phase_kernel, dim3(NB*HH), dim3(512), 0, stream,
                       x, w, csf, bias, out, cnt, wl, cap);
    hipLaunchKernelGGL(fixup_kernel, dim3(256), dim3(256), 0, stream,
                       x, w, csd, bias, cnt, wl, cap, out);
}

// Round 4
// 972.991 us; speedup vs baseline: 1.2631x; 1.2631x over previous
//
#include <hip/hip_runtime.h>
#include <hip/hip_bf16.h>
#include <math.h>

#define NB   16
#define CIN  128
#define COUT 128
#define HH   56
#define WW   56
#define LL   (HH*WW)          // 3136
#define NOC2 256

typedef __attribute__((ext_vector_type(8))) short short8;
typedef __attribute__((ext_vector_type(16))) float f32x16;
typedef __attribute__((ext_vector_type(4))) unsigned int uint4v;

// ---- workspace layout (bytes) ----
//  [0,4)                 worklist counter
//  [256, +18432)         fp64 cos/sin tables [2][9][128]
//  [32768, +1179648)     bf16 split folded weights wsp[hi/lo][9][256 oc2][128 c]
//  [1212416, ...)        worklist entries
#define CSD_OFF 256
#define WSP_OFF 32768
#define WL_OFF  (WSP_OFF + 2*9*NOC2*CIN*2)

#define TAU_A 3e-4f
#define TAU_B 3e-5f

// ---------------- prep: fp64 tables + folded/split weights ----------------
__global__ void prep_kernel(const float* __restrict__ w, const float* __restrict__ bk,
                            double* __restrict__ csd, unsigned short* __restrict__ wsp) {
    int i = blockIdx.x * 256 + threadIdx.x;
    if (i < 2*9*128) {
        int s = i / (9*128);
        int rem = i - s*(9*128);
        double v = (double)bk[rem];
        csd[i] = (s == 0) ? cos(v) : sin(v);
    }
    if (i < 9*128*128) {
        int k = i / (128*128);
        int rem = i - k*(128*128);
        int oc = rem >> 7, c = rem & 127;
        double bkv = (double)bk[k*128 + oc];
        float wv = w[i];
        float fa = (float)(cos(bkv) * (double)wv);
        float fb = (float)(sin(bkv) * (double)wv);
        __hip_bfloat16 ah = __float2bfloat16(fa);
        __hip_bfloat16 al = __float2bfloat16(fa - __bfloat162float(ah));
        __hip_bfloat16 bh = __float2bfloat16(fb);
        __hip_bfloat16 bl = __float2bfloat16(fb - __bfloat162float(bh));
        size_t base  = ((size_t)k*NOC2)*128;
        size_t lo    = (size_t)9*NOC2*128;
        wsp[base + (size_t)oc*128 + c]              = *(unsigned short*)&ah;
        wsp[base + (size_t)(128+oc)*128 + c]        = *(unsigned short*)&bh;
        wsp[lo + base + (size_t)oc*128 + c]         = *(unsigned short*)&al;
        wsp[lo + base + (size_t)(128+oc)*128 + c]   = *(unsigned short*)&bl;
    }
}

// ---------------- main MFMA kernel ----------------
#define PXT 128
#define NPXT 25               // ceil(3136/128), last tile has 64 valid px
#define CPITCH 24             // ushort slots per pixel: 16 ch + 8 pad = 48B
#define XROWS 6
#define XCOLS 58
#define XS_N (XROWS*XCOLS*CPITCH)   // 8352 ushort per (hi|lo)
#define WS_N (128*CPITCH)           // 3072 ushort per (hi|lo)

__global__ __launch_bounds__(256, 3)
void mfma_kernel(const float* __restrict__ x, const unsigned short* __restrict__ wsp,
                 const float* __restrict__ bias, float* __restrict__ out,
                 unsigned* __restrict__ cnt, unsigned* __restrict__ wl, unsigned cap)
{
    __shared__ __align__(16) unsigned short sm_x[2*XS_N];   // hi then lo: 33408 B
    __shared__ __align__(16) unsigned short sm_w[2*WS_N];   // hi then lo: 12288 B
    __shared__ float sm_bias[64];

    const int tid = threadIdx.x;
    int bid = blockIdx.x;
    const int ocb = bid & 1; bid >>= 1;
    const int pxt = bid % NPXT;
    const int bat = bid / NPXT;
    const int l0  = pxt * PXT;
    const int o0  = ocb * 64;
    const int y_first = l0 / WW;

    const int lane = tid & 63;
    const int n    = lane & 31;
    const int kh   = lane >> 5;
    const int wave = tid >> 6;
    const int wr   = wave >> 1;     // oc-tile pair (0/1)
    const int wpx  = wave & 1;      // px pair (0/1)

    // per-lane pixel bases for the wave's two px-tiles (clamped for addressing)
    const int p0 = l0 + wpx*64 + n;
    const int p1 = p0 + 32;
    int pc0 = p0 < LL ? p0 : LL-1;
    int pc1 = p1 < LL ? p1 : LL-1;
    int y0 = pc0 / WW, xx0 = pc0 - y0*WW;
    int y1 = pc1 / WW, xx1 = pc1 - y1*WW;
    const int bB0 = ((y0 - y_first)*XCOLS + xx0)*(CPITCH*2) + kh*16;
    const int bB1 = ((y1 - y_first)*XCOLS + xx1)*(CPITCH*2) + kh*16;
    const int bA  = (wr*32 + n)*(CPITCH*2) + kh*16;

    if (tid < 64) sm_bias[tid] = bias[o0 + tid];

    f32x16 acc[4];  // [0]=a,px0  [1]=a,px1  [2]=b,px0  [3]=b,px1
    #pragma unroll
    for (int t = 0; t < 4; t++)
        #pragma unroll
        for (int r = 0; r < 16; r++) acc[t][r] = 0.f;

    const float* xb = x + (size_t)bat * CIN * LL;
    const char* smx = (const char*)sm_x;
    const char* smw = (const char*)sm_w;

    for (int ch = 0; ch < 8; ch++) {
        const int c0 = ch * 16;
        __syncthreads();
        // stage x tile: 16 ch x 6 rows x 58 cols, hi/lo split
        for (int s = tid; s < 16*XROWS*XCOLS; s += 256) {
            int cc  = s / (XROWS*XCOLS);
            int rem = s - cc*(XROWS*XCOLS);
            int r   = rem / XCOLS;
            int col = rem - r*XCOLS;
            int gr = y_first - 1 + r;
            int gc = col - 1;
            float v = 0.f;
            if ((unsigned)gr < HH && (unsigned)gc < WW)
                v = xb[(size_t)(c0+cc)*LL + gr*WW + gc];
            __hip_bfloat16 h = __float2bfloat16(v);
            __hip_bfloat16 l = __float2bfloat16(v - __bfloat162float(h));
            int off = (r*XCOLS + col)*CPITCH + cc;
            sm_x[off]        = *(unsigned short*)&h;
            sm_x[XS_N + off] = *(unsigned short*)&l;
        }
        #pragma unroll
        for (int tap = 0; tap < 9; tap++) {
            const int ky = tap / 3, kx = tap - 3*(tap/3);
            __syncthreads();
            // stage weights for (tap, chunk): LDS rows 0..63 = a(ocs o0..), 64..127 = b(same ocs)
            {
                int s   = tid;          // exactly 256 8-ch groups
                int row = s >> 1;
                int cg  = s & 1;
                int oc2 = (row < 64) ? (o0 + row) : (128 + o0 + (row - 64));
                size_t gsrc = ((size_t)tap*NOC2 + oc2)*128 + c0 + cg*8;
                uint4v hv = *(const uint4v*)(wsp + gsrc);
                uint4v lv = *(const uint4v*)(wsp + (size_t)9*NOC2*128 + gsrc);
                int doff = row*CPITCH + cg*8;
                *(uint4v*)(sm_w + doff)        = hv;
                *(uint4v*)(sm_w + WS_N + doff) = lv;
            }
            __syncthreads();
            const int toff = (ky*XCOLS + kx) * (CPITCH*2);
            short8 Ah0 = *(const short8*)(smw + bA);
            short8 Ah1 = *(const short8*)(smw + bA + 64*CPITCH*2);
            short8 Al0 = *(const short8*)(smw + bA + 2*WS_N);
            short8 Al1 = *(const short8*)(smw + bA + 2*WS_N + 64*CPITCH*2);
            short8 Bh0 = *(const short8*)(smx + bB0 + toff);
            short8 Bh1 = *(const short8*)(smx + bB1 + toff);
            short8 Bl0 = *(const short8*)(smx + bB0 + toff + 2*XS_N);
            short8 Bl1 = *(const short8*)(smx + bB1 + toff + 2*XS_N);
            acc[0] = __builtin_amdgcn_mfma_f32_32x32x16_bf16(Al0, Bh0, acc[0], 0,0,0);
            acc[0] = __builtin_amdgcn_mfma_f32_32x32x16_bf16(Ah0, Bl0, acc[0], 0,0,0);
            acc[0] = __builtin_amdgcn_mfma_f32_32x32x16_bf16(Ah0, Bh0, acc[0], 0,0,0);
            acc[1] = __builtin_amdgcn_mfma_f32_32x32x16_bf16(Al0, Bh1, acc[1], 0,0,0);
            acc[1] = __builtin_amdgcn_mfma_f32_32x32x16_bf16(Ah0, Bl1, acc[1], 0,0,0);
            acc[1] = __builtin_amdgcn_mfma_f32_32x32x16_bf16(Ah0, Bh1, acc[1], 0,0,0);
            acc[2] = __builtin_amdgcn_mfma_f32_32x32x16_bf16(Al1, Bh0, acc[2], 0,0,0);
            acc[2] = __builtin_amdgcn_mfma_f32_32x32x16_bf16(Ah1, Bl0, acc[2], 0,0,0);
            acc[2] = __builtin_amdgcn_mfma_f32_32x32x16_bf16(Ah1, Bh0, acc[2], 0,0,0);
            acc[3] = __builtin_amdgcn_mfma_f32_32x32x16_bf16(Al1, Bh1, acc[3], 0,0,0);
            acc[3] = __builtin_amdgcn_mfma_f32_32x32x16_bf16(Ah1, Bl1, acc[3], 0,0,0);
            acc[3] = __builtin_amdgcn_mfma_f32_32x32x16_bf16(Ah1, Bh1, acc[3], 0,0,0);
        }
    }

    // ---- epilogue: a/bb are in-register pairs; theta + magnitude + stores ----
    const float eps = 1e-05f;
    const float PIf = 3.14159265358979323846f;
    size_t obase = (size_t)bat * (2*COUT) * LL;

    #pragma unroll
    for (int j = 0; j < 2; j++) {
        int p = j ? p1 : p0;
        if (p < LL) {
            #pragma unroll
            for (int r = 0; r < 16; r++) {
                int row = (r & 3) + 8*(r >> 2) + 4*kh;
                int oc  = o0 + wr*32 + row;
                float av = acc[j][r];
                float bv = acc[2+j][r];
                if (fabsf(av) < TAU_A || fabsf(bv) < TAU_B) {
                    unsigned slot = atomicAdd(cnt, 1u);
                    if (slot < cap)
                        wl[slot] = ((unsigned)(bat*LL + p) << 7) | (unsigned)oc;
                }
                bool ag = av > 0.f, bg = bv > 0.f;
                bool eq = (ag == bg);
                float ratio = eq ? (bv / (av + eps)) : (av / (bv + eps));
                float at = atanf(ratio);
                if (!eq) at = -at;
                float peak = eq ? (ag ? PIf*0.5f : -PIf*0.5f) : (bg ? 0.0f : -PIf);
                float th = peak - at;
                float o  = sinf(th)*av + cosf(th)*bv + sm_bias[wr*32 + row];
                out[obase + (size_t)oc*LL + p]          = o;
                out[obase + (size_t)(COUT+oc)*LL + p]   = th * (1.0f/PIf);
            }
        }
    }
}

// ---------------- fp64 fixup for near-discontinuity elements ----------------
__global__ __launch_bounds__(256)
void fixup_kernel(const float* __restrict__ x, const float* __restrict__ w,
                  const double* __restrict__ csd, const float* __restrict__ bias,
                  const unsigned* __restrict__ cnt, const unsigned* __restrict__ wl,
                  unsigned cap, float* __restrict__ out) {
    const int lane   = threadIdx.x & 63;
    const int waveid = (blockIdx.x * 256 + threadIdx.x) >> 6;
    const int nwaves = gridDim.x * 4;
    unsigned nf = *cnt; if (nf > cap) nf = cap;
    const double PI = 3.14159265358979323846;

    for (unsigned u = waveid; u < nf; u += nwaves) {
        unsigned idx = wl[u];
        int oc = idx & 127;
        unsigned rest = idx >> 7;
        int bb_ = rest / LL;
        int l   = rest - bb_*LL;
        int yy  = l / WW;
        int xx  = l - yy*WW;
        const float* xb = x + (size_t)bb_ * CIN * LL;

        double pa = 0.0, pb = 0.0;
        #pragma unroll
        for (int k = 0; k < 9; k++) {
            int dy = k/3, dx = k - dy*3;
            int py = yy + dy - 1, px = xx + dx - 1;
            double pk = 0.0;
            if ((unsigned)py < HH && (unsigned)px < WW) {
                int base = py*WW + px;
                const float* wr = w + k*(COUT*CIN) + oc*CIN;
                int c = lane;
                pk  = (double)xb[(size_t)c*LL + base] * (double)wr[c];
                c = lane + 64;
                pk += (double)xb[(size_t)c*LL + base] * (double)wr[c];
            }
            pa += csd[k*COUT + oc] * pk;
            pb += csd[9*COUT + k*COUT + oc] * pk;
        }
        #pragma unroll
        for (int off = 32; off > 0; off >>= 1) {
            pa += __shfl_xor(pa, off, 64);
            pb += __shfl_xor(pb, off, 64);
        }
        if (lane == 0) {
            bool ag = pa > 0.0, bg = pb > 0.0;
            bool eq = (ag == bg);
            double th;
            if (eq) th = (ag ? PI*0.5 : -PI*0.5) - atan(pb / (pa + 1e-5));
            else    th = (bg ? 0.0 : -PI) + atan(pa / (pb + 1e-5));
            double o = sin(th)*pa + cos(th)*pb + (double)bias[oc];
            out[((size_t)bb_*(2*COUT) + oc) * LL + l]        = (float)o;
            out[((size_t)bb_*(2*COUT) + COUT + oc) * LL + l] = (float)(th / PI);
        }
    }
}

extern "C" void kernel_launch(void* const* d_in, const int* in_sizes, int n_in,
                              void* d_out, int out_size, void* d_ws, size_t ws_size,
                              hipStream_t stream) {
    const float* x    = (const float*)d_in[0];
    const float* w    = (const float*)d_in[1];
    const float* bk   = (const float*)d_in[2];
    const float* bias = (const float*)d_in[3];
    float* out = (float*)d_out;

    char* ws = (char*)d_ws;
    unsigned*       cnt = (unsigned*)ws;
    double*         csd = (double*)(ws + CSD_OFF);
    unsigned short* wsp = (unsigned short*)(ws + WSP_OFF);
    unsigned*       wl  = (unsigned*)(ws + WL_OFF);
    unsigned cap = (ws_size > (size_t)WL_OFF + 4096) ? (unsigned)((ws_size - WL_OFF) / 4) : 0u;

    hipMemsetAsync(cnt, 0, 4, stream);
    hipLaunchKernelGGL(prep_kernel, dim3(576), dim3(256), 0, stream, w, bk, csd, wsp);
    hipLaunchKernelGGL(mfma_kernel, dim3(NB*NPXT*2), dim3(256), 0, stream,
                       x, wsp, bias, out, cnt, wl, cap);
    hipLaunchKernelGGL(fixup_kernel, dim3(512), dim3(256), 0, stream,
                       x, w, csd, bias, cnt, wl, cap, out);
}